// Round 1
// baseline (2019.814 us; speedup 1.0000x reference)
//
#include <hip/hip_runtime.h>
#include <cstddef>

#define F 128
#define EPSV 1e-5f

// ---- deg init (self loop = 1) + zero BN stat accumulators ----
__global__ __launch_bounds__(256) void k_init(float* __restrict__ deg,
                                              float* __restrict__ stats, int n) {
  int i = blockIdx.x * 256 + threadIdx.x;
  if (i < n) deg[i] = 1.0f;
  if (i < 256) stats[i] = 0.0f;  // [0..127]=sum, [128..255]=sumsq
}

// ---- degree count over edge targets ----
__global__ __launch_bounds__(256) void k_deg(const int* __restrict__ col,
                                             float* __restrict__ deg, int e) {
  int i = blockIdx.x * 256 + threadIdx.x;
  if (i < e) atomicAdd(&deg[col[i]], 1.0f);
}

// ---- dinv = rsqrt(deg), in place ----
__global__ __launch_bounds__(256) void k_dinv(float* __restrict__ deg, int n) {
  int i = blockIdx.x * 256 + threadIdx.x;
  if (i < n) deg[i] = rsqrtf(deg[i]);
}

// ---- h = x @ W  (fp32, W in LDS, 32-row x tile, 4x4 register blocking) ----
__global__ __launch_bounds__(256) void k_gemm(const float* __restrict__ x,
                                              const float* __restrict__ Wm,
                                              float* __restrict__ h, int n) {
  __shared__ float Ws[F * F];      // 64 KB
  __shared__ float xs[32][F];      // 16 KB
  int t = threadIdx.x;
  const float4* W4 = (const float4*)Wm;
  float4* Ws4 = (float4*)Ws;
  for (int i = t; i < F * F / 4; i += 256) Ws4[i] = W4[i];
  int row0 = blockIdx.x * 32;
  int rows = n - row0; if (rows > 32) rows = 32;
  const float4* x4 = (const float4*)(x + (size_t)row0 * F);
  float4* xs4 = (float4*)&xs[0][0];
  for (int i = t; i < rows * (F / 4); i += 256) xs4[i] = x4[i];
  __syncthreads();

  int ct = t & 31;         // 32 col-groups of 4
  int rt = t >> 5;         // 8 row-groups of 4
  int c0 = ct * 4;
  int r0 = rt * 4;
  float acc[4][4] = {{0.f}};
  for (int k = 0; k < F; k += 4) {
    float4 xv[4];
#pragma unroll
    for (int r = 0; r < 4; ++r) xv[r] = *(const float4*)&xs[r0 + r][k];
#pragma unroll
    for (int kk = 0; kk < 4; ++kk) {
      float4 wv = *(const float4*)&Ws[(k + kk) * F + c0];
#pragma unroll
      for (int r = 0; r < 4; ++r) {
        float xk = (kk == 0) ? xv[r].x : (kk == 1) ? xv[r].y : (kk == 2) ? xv[r].z : xv[r].w;
        acc[r][0] += xk * wv.x;
        acc[r][1] += xk * wv.y;
        acc[r][2] += xk * wv.z;
        acc[r][3] += xk * wv.w;
      }
    }
  }
#pragma unroll
  for (int r = 0; r < 4; ++r) {
    int gr = row0 + r0 + r;
    if (gr < n) {
      float4 o; o.x = acc[r][0]; o.y = acc[r][1]; o.z = acc[r][2]; o.w = acc[r][3];
      *(float4*)&h[(size_t)gr * F + c0] = o;
    }
  }
}

// ---- out = b + h*dinv^2 (self loop contribution), fully overwrites d_out ----
__global__ __launch_bounds__(256) void k_initout(const float* __restrict__ h,
                                                 const float* __restrict__ dinv,
                                                 const float* __restrict__ b,
                                                 float* __restrict__ out, int n) {
  long long i4 = (long long)blockIdx.x * 256 + threadIdx.x;
  if (i4 >= (long long)n * (F / 4)) return;
  int node = (int)(i4 >> 5);
  int c0 = ((int)i4 & 31) * 4;
  float d = dinv[node];
  float d2 = d * d;
  float4 hv = *(const float4*)(h + (size_t)node * F + c0);
  float4 bv = *(const float4*)(b + c0);
  float4 o;
  o.x = bv.x + hv.x * d2; o.y = bv.y + hv.y * d2;
  o.z = bv.z + hv.z * d2; o.w = bv.w + hv.w * d2;
  *(float4*)(out + (size_t)node * F + c0) = o;
}

// ---- edge scatter: out[col] += h[row] * dinv[row]*dinv[col]  (atomic f32) ----
__global__ __launch_bounds__(256) void k_scatter(const int* __restrict__ row,
                                                 const int* __restrict__ col,
                                                 const float* __restrict__ dinv,
                                                 const float* __restrict__ h,
                                                 float* __restrict__ out, int e) {
  long long gid = (long long)blockIdx.x * 256 + threadIdx.x;
  if (gid >= (long long)e * F) return;
  int ed = (int)(gid >> 7);
  int f = (int)gid & (F - 1);
  int r = row[ed], c = col[ed];
  float nrm = dinv[r] * dinv[c];
  atomicAdd(out + (size_t)c * F + f, h[(size_t)r * F + f] * nrm);
}

// ---- BN partial stats: per-feature sum / sumsq ----
__global__ __launch_bounds__(256) void k_stats(const float* __restrict__ out,
                                               float* __restrict__ stats, int n) {
  int f = threadIdx.x & (F - 1);
  int half = threadIdx.x >> 7;  // 0/1
  int rpb = (n + gridDim.x - 1) / gridDim.x;
  int r0 = blockIdx.x * rpb;
  int r1 = r0 + rpb; if (r1 > n) r1 = n;
  float s = 0.f, ss = 0.f;
  for (int r = r0 + half; r < r1; r += 2) {
    float v = out[(size_t)r * F + f];
    s += v; ss += v * v;
  }
  __shared__ float sh[2][F][2];
  sh[0][f][half] = s; sh[1][f][half] = ss;
  __syncthreads();
  if (half == 0) {
    atomicAdd(&stats[f], sh[0][f][0] + sh[0][f][1]);
    atomicAdd(&stats[F + f], sh[1][f][0] + sh[1][f][1]);
  }
}

// ---- finalize scale/shift ----
__global__ void k_fin(float* __restrict__ stats, const float* __restrict__ gamma,
                      const float* __restrict__ beta, int n) {
  int f = threadIdx.x;
  if (f >= F) return;
  float inv_n = 1.0f / (float)n;
  float mean = stats[f] * inv_n;
  float var = stats[F + f] * inv_n - mean * mean;
  float scale = gamma[f] * rsqrtf(var + EPSV);
  stats[2 * F + f] = scale;
  stats[3 * F + f] = beta[f] - mean * scale;
}

// ---- apply BN + ReLU in place on d_out ----
__global__ __launch_bounds__(256) void k_apply(float* __restrict__ out,
                                               const float* __restrict__ stats, int n) {
  long long i4 = (long long)blockIdx.x * 256 + threadIdx.x;
  if (i4 >= (long long)n * (F / 4)) return;
  int c0 = ((int)i4 & 31) * 4;
  float4 v = *(const float4*)(out + i4 * 4);
  float4 sc = *(const float4*)(stats + 2 * F + c0);
  float4 sf = *(const float4*)(stats + 3 * F + c0);
  float4 o;
  o.x = fmaxf(v.x * sc.x + sf.x, 0.f);
  o.y = fmaxf(v.y * sc.y + sf.y, 0.f);
  o.z = fmaxf(v.z * sc.z + sf.z, 0.f);
  o.w = fmaxf(v.w * sc.w + sf.w, 0.f);
  *(float4*)(out + i4 * 4) = o;
}

extern "C" void kernel_launch(void* const* d_in, const int* in_sizes, int n_in,
                              void* d_out, int out_size, void* d_ws, size_t ws_size,
                              hipStream_t stream) {
  const float* x     = (const float*)d_in[0];
  const int*   ei    = (const int*)d_in[1];
  const float* W     = (const float*)d_in[2];
  const float* b     = (const float*)d_in[3];
  const float* gamma = (const float*)d_in[4];
  const float* beta  = (const float*)d_in[5];
  int n = in_sizes[0] / F;
  int e = in_sizes[1] / 2;
  const int* row = ei;       // edge_index[0] = sources
  const int* col = ei + e;   // edge_index[1] = targets

  float* out   = (float*)d_out;
  float* h     = (float*)d_ws;                 // n*F floats (51.2 MB)
  float* deg   = h + (size_t)n * F;            // n floats (doubles as dinv)
  float* stats = deg + n;                      // 512 floats

  k_init<<<(n + 255) / 256, 256, 0, stream>>>(deg, stats, n);
  k_deg<<<(e + 255) / 256, 256, 0, stream>>>(col, deg, e);
  k_dinv<<<(n + 255) / 256, 256, 0, stream>>>(deg, n);
  k_gemm<<<(n + 31) / 32, 256, 0, stream>>>(x, W, h, n);
  k_initout<<<(int)(((long long)n * (F / 4) + 255) / 256), 256, 0, stream>>>(h, deg, b, out, n);
  k_scatter<<<(int)(((long long)e * F + 255) / 256), 256, 0, stream>>>(row, col, deg, h, out, e);
  k_stats<<<400, 256, 0, stream>>>(out, stats, n);
  k_fin<<<1, F, 0, stream>>>(stats, gamma, beta, n);
  k_apply<<<(int)(((long long)n * (F / 4) + 255) / 256), 256, 0, stream>>>(out, stats, n);
}

// Round 2
// 914.882 us; speedup vs baseline: 2.2077x; 2.2077x over previous
//
#include <hip/hip_runtime.h>
#include <cstddef>

#define F 128
#define BM 64
#define EPSV 1e-5f

// ---- deg init (self loop = 1) + zero BN stat accumulators ----
__global__ __launch_bounds__(256) void k_init(float* __restrict__ deg,
                                              float* __restrict__ stats, int n) {
  int i = blockIdx.x * 256 + threadIdx.x;
  if (i < n) deg[i] = 1.0f;
  if (i < 256) stats[i] = 0.0f;  // [0..127]=sum, [128..255]=sumsq
}

// ---- degree count over edge targets ----
__global__ __launch_bounds__(256) void k_deg(const int* __restrict__ col,
                                             float* __restrict__ deg, int e) {
  int i = blockIdx.x * 256 + threadIdx.x;
  if (i < e) atomicAdd(&deg[col[i]], 1.0f);
}

// ---- dinv = rsqrt(deg), in place ----
__global__ __launch_bounds__(256) void k_dinv(float* __restrict__ deg, int n) {
  int i = blockIdx.x * 256 + threadIdx.x;
  if (i < n) deg[i] = rsqrtf(deg[i]);
}

// ---- h = x @ W (fp32) + fused out-init: out = b + h*dinv^2 ----
// BM=64 rows/block, 256 threads, thread = 8 rows x 4 cols, acc 32 regs.
// LDS: W 64KB + x-tile 32KB = 96KB -> 1 block/CU, 4 waves.
// #pragma unroll 2 pins the k-loop (R1: full unroll -> 256 VGPR + spills).
__global__ __launch_bounds__(256) void k_gemm(const float* __restrict__ x,
                                              const float* __restrict__ Wm,
                                              const float* __restrict__ dinv,
                                              const float* __restrict__ b,
                                              float* __restrict__ h,
                                              float* __restrict__ out, int n) {
  __shared__ float Ws[F * F];    // 64 KB
  __shared__ float xs[BM * F];   // 32 KB
  int t = threadIdx.x;
  {
    const float4* W4 = (const float4*)Wm;
    float4* Ws4 = (float4*)Ws;
#pragma unroll
    for (int i = 0; i < (F * F / 4) / 256; ++i) Ws4[t + i * 256] = W4[t + i * 256];
  }
  int row0 = blockIdx.x * BM;
  int rows = n - row0; if (rows > BM) rows = BM;
  {
    const float4* x4 = (const float4*)(x + (size_t)row0 * F);
    float4* xs4 = (float4*)xs;
    for (int i = t; i < rows * (F / 4); i += 256) xs4[i] = x4[i];
  }
  __syncthreads();

  int c0 = (t & 31) * 4;   // 32 col-groups of 4
  int r0 = (t >> 5) * 8;   // 8 row-groups of 8
  float acc[8][4] = {{0.f}};
#pragma unroll 2
  for (int k = 0; k < F; k += 4) {
    float4 wv[4];
#pragma unroll
    for (int kk = 0; kk < 4; ++kk) wv[kk] = *(const float4*)&Ws[(k + kk) * F + c0];
#pragma unroll
    for (int r = 0; r < 8; ++r) {
      float4 xv = *(const float4*)&xs[(r0 + r) * F + k];  // 2-addr broadcast in wave
      acc[r][0] = fmaf(xv.x, wv[0].x, acc[r][0]);
      acc[r][1] = fmaf(xv.x, wv[0].y, acc[r][1]);
      acc[r][2] = fmaf(xv.x, wv[0].z, acc[r][2]);
      acc[r][3] = fmaf(xv.x, wv[0].w, acc[r][3]);
      acc[r][0] = fmaf(xv.y, wv[1].x, acc[r][0]);
      acc[r][1] = fmaf(xv.y, wv[1].y, acc[r][1]);
      acc[r][2] = fmaf(xv.y, wv[1].z, acc[r][2]);
      acc[r][3] = fmaf(xv.y, wv[1].w, acc[r][3]);
      acc[r][0] = fmaf(xv.z, wv[2].x, acc[r][0]);
      acc[r][1] = fmaf(xv.z, wv[2].y, acc[r][1]);
      acc[r][2] = fmaf(xv.z, wv[2].z, acc[r][2]);
      acc[r][3] = fmaf(xv.z, wv[2].w, acc[r][3]);
      acc[r][0] = fmaf(xv.w, wv[3].x, acc[r][0]);
      acc[r][1] = fmaf(xv.w, wv[3].y, acc[r][1]);
      acc[r][2] = fmaf(xv.w, wv[3].z, acc[r][2]);
      acc[r][3] = fmaf(xv.w, wv[3].w, acc[r][3]);
    }
  }

  float4 bv = *(const float4*)&b[c0];
#pragma unroll
  for (int r = 0; r < 8; ++r) {
    int gr = row0 + r0 + r;
    if (gr < n) {
      float dv = dinv[gr];
      float d2 = dv * dv;
      float4 hv; hv.x = acc[r][0]; hv.y = acc[r][1]; hv.z = acc[r][2]; hv.w = acc[r][3];
      *(float4*)&h[(size_t)gr * F + c0] = hv;
      float4 ov;
      ov.x = bv.x + hv.x * d2; ov.y = bv.y + hv.y * d2;
      ov.z = bv.z + hv.z * d2; ov.w = bv.w + hv.w * d2;
      *(float4*)&out[(size_t)gr * F + c0] = ov;
    }
  }
}

// ---- edge scatter: out[col] += h[row] * dinv[row]*dinv[col]  (atomic f32) ----
__global__ __launch_bounds__(256) void k_scatter(const int* __restrict__ row,
                                                 const int* __restrict__ col,
                                                 const float* __restrict__ dinv,
                                                 const float* __restrict__ h,
                                                 float* __restrict__ out, int e) {
  long long gid = (long long)blockIdx.x * 256 + threadIdx.x;
  if (gid >= (long long)e * F) return;
  int ed = (int)(gid >> 7);
  int f = (int)gid & (F - 1);
  int r = row[ed], c = col[ed];
  float nrm = dinv[r] * dinv[c];
  atomicAdd(out + (size_t)c * F + f, h[(size_t)r * F + f] * nrm);
}

// ---- BN partial stats: per-feature sum / sumsq ----
__global__ __launch_bounds__(256) void k_stats(const float* __restrict__ out,
                                               float* __restrict__ stats, int n) {
  int f = threadIdx.x & (F - 1);
  int half = threadIdx.x >> 7;  // 0/1
  int rpb = (n + gridDim.x - 1) / gridDim.x;
  int r0 = blockIdx.x * rpb;
  int r1 = r0 + rpb; if (r1 > n) r1 = n;
  float s = 0.f, ss = 0.f;
  for (int r = r0 + half; r < r1; r += 2) {
    float v = out[(size_t)r * F + f];
    s += v; ss += v * v;
  }
  __shared__ float sh[2][F][2];
  sh[0][f][half] = s; sh[1][f][half] = ss;
  __syncthreads();
  if (half == 0) {
    atomicAdd(&stats[f], sh[0][f][0] + sh[0][f][1]);
    atomicAdd(&stats[F + f], sh[1][f][0] + sh[1][f][1]);
  }
}

// ---- finalize scale/shift ----
__global__ void k_fin(float* __restrict__ stats, const float* __restrict__ gamma,
                      const float* __restrict__ beta, int n) {
  int f = threadIdx.x;
  if (f >= F) return;
  float inv_n = 1.0f / (float)n;
  float mean = stats[f] * inv_n;
  float var = stats[F + f] * inv_n - mean * mean;
  float scale = gamma[f] * rsqrtf(var + EPSV);
  stats[2 * F + f] = scale;
  stats[3 * F + f] = beta[f] - mean * scale;
}

// ---- apply BN + ReLU in place on d_out ----
__global__ __launch_bounds__(256) void k_apply(float* __restrict__ out,
                                               const float* __restrict__ stats, int n) {
  long long i4 = (long long)blockIdx.x * 256 + threadIdx.x;
  if (i4 >= (long long)n * (F / 4)) return;
  int c0 = ((int)i4 & 31) * 4;
  float4 v = *(const float4*)(out + i4 * 4);
  float4 sc = *(const float4*)(stats + 2 * F + c0);
  float4 sf = *(const float4*)(stats + 3 * F + c0);
  float4 o;
  o.x = fmaxf(v.x * sc.x + sf.x, 0.f);
  o.y = fmaxf(v.y * sc.y + sf.y, 0.f);
  o.z = fmaxf(v.z * sc.z + sf.z, 0.f);
  o.w = fmaxf(v.w * sc.w + sf.w, 0.f);
  *(float4*)(out + i4 * 4) = o;
}

extern "C" void kernel_launch(void* const* d_in, const int* in_sizes, int n_in,
                              void* d_out, int out_size, void* d_ws, size_t ws_size,
                              hipStream_t stream) {
  const float* x     = (const float*)d_in[0];
  const int*   ei    = (const int*)d_in[1];
  const float* W     = (const float*)d_in[2];
  const float* b     = (const float*)d_in[3];
  const float* gamma = (const float*)d_in[4];
  const float* beta  = (const float*)d_in[5];
  int n = in_sizes[0] / F;
  int e = in_sizes[1] / 2;
  const int* row = ei;       // edge_index[0] = sources
  const int* col = ei + e;   // edge_index[1] = targets

  float* out   = (float*)d_out;
  float* h     = (float*)d_ws;                 // n*F floats (51.2 MB)
  float* deg   = h + (size_t)n * F;            // n floats (doubles as dinv)
  float* stats = deg + n;                      // 512 floats

  k_init<<<(n + 255) / 256, 256, 0, stream>>>(deg, stats, n);
  k_deg<<<(e + 255) / 256, 256, 0, stream>>>(col, deg, e);
  k_dinv<<<(n + 255) / 256, 256, 0, stream>>>(deg, n);
  k_gemm<<<(n + BM - 1) / BM, 256, 0, stream>>>(x, W, deg, b, h, out, n);
  k_scatter<<<(int)(((long long)e * F + 255) / 256), 256, 0, stream>>>(row, col, deg, h, out, e);
  k_stats<<<400, 256, 0, stream>>>(out, stats, n);
  k_fin<<<1, F, 0, stream>>>(stats, gamma, beta, n);
  k_apply<<<(int)(((long long)n * (F / 4) + 255) / 256), 256, 0, stream>>>(out, stats, n);
}

// Round 3
// 448.880 us; speedup vs baseline: 4.4997x; 2.0381x over previous
//
#include <hip/hip_runtime.h>
#include <cstddef>

#define F 128
#define BM 64
#define EPSV 1e-5f
#define SB 1024  // elements per scan block (256 threads x 4)

// ---- zero deg + BN stat accumulators ----
__global__ __launch_bounds__(256) void k_zero(int* __restrict__ deg,
                                              float* __restrict__ stats, int n) {
  int i = blockIdx.x * 256 + threadIdx.x;
  if (i < n) deg[i] = 0;
  if (i < 256) stats[i] = 0.0f;  // [0..127]=sum, [128..255]=sumsq
}

// ---- in-degree count over edge targets (int atomics) ----
__global__ __launch_bounds__(256) void k_degc(const int* __restrict__ col,
                                              int* __restrict__ deg, int e) {
  int i = blockIdx.x * 256 + threadIdx.x;
  if (i < e) atomicAdd(&deg[col[i]], 1);
}

// ---- scan pass 1: per-block exclusive scan of deg, block sums out ----
__global__ __launch_bounds__(256) void k_scan1(const int* __restrict__ deg,
                                               int* __restrict__ rowptr,
                                               int* __restrict__ bsum, int n) {
  __shared__ int sh[256];
  int t = threadIdx.x;
  int i0 = blockIdx.x * SB + t * 4;
  int d0 = 0, d1 = 0, d2 = 0, d3 = 0;
  if (i0 + 3 < n) {
    int4 d = *(const int4*)&deg[i0];
    d0 = d.x; d1 = d.y; d2 = d.z; d3 = d.w;
  } else {
    if (i0 + 0 < n) d0 = deg[i0];
    if (i0 + 1 < n) d1 = deg[i0 + 1];
    if (i0 + 2 < n) d2 = deg[i0 + 2];
    if (i0 + 3 < n) d3 = deg[i0 + 3];
  }
  int s = d0 + d1 + d2 + d3;
  sh[t] = s;
  __syncthreads();
  for (int off = 1; off < 256; off <<= 1) {
    int v = (t >= off) ? sh[t - off] : 0;
    __syncthreads();
    sh[t] += v;
    __syncthreads();
  }
  if (t == 255) bsum[blockIdx.x] = sh[255];
  int p = sh[t] - s;  // exclusive prefix of this thread's 4 elements
  if (i0 + 0 < n) rowptr[i0 + 0] = p; p += d0;
  if (i0 + 1 < n) rowptr[i0 + 1] = p; p += d1;
  if (i0 + 2 < n) rowptr[i0 + 2] = p; p += d2;
  if (i0 + 3 < n) rowptr[i0 + 3] = p;
}

// ---- scan pass 2: serial exclusive scan of ~98 block sums ----
__global__ void k_scan2(int* __restrict__ bsum, int nblk,
                        int* __restrict__ rowptr, int n, int e) {
  if (threadIdx.x == 0) {
    int run = 0;
    for (int i = 0; i < nblk; ++i) { int v = bsum[i]; bsum[i] = run; run += v; }
    rowptr[n] = e;
  }
}

// ---- scan pass 3: add block base; init cursor; dinv = rsqrt(1+deg) ----
__global__ __launch_bounds__(256) void k_scan3(const int* __restrict__ deg,
                                               int* __restrict__ rowptr,
                                               int* __restrict__ cursor,
                                               float* __restrict__ dinv,
                                               const int* __restrict__ bsum, int n) {
  int i = blockIdx.x * 256 + threadIdx.x;
  if (i >= n) return;
  int rp = rowptr[i] + bsum[i / SB];
  rowptr[i] = rp;
  cursor[i] = rp;
  dinv[i] = rsqrtf((float)(1 + deg[i]));
}

// ---- counting-sort fill: src_sorted bucketed by target node ----
__global__ __launch_bounds__(256) void k_fill(const int* __restrict__ row,
                                              const int* __restrict__ col,
                                              int* __restrict__ cursor,
                                              int* __restrict__ src_sorted, int e) {
  int i = blockIdx.x * 256 + threadIdx.x;
  if (i >= e) return;
  int pos = atomicAdd(&cursor[col[i]], 1);
  src_sorted[pos] = row[i];
}

// ---- h = x @ W (fp32). x-tile in LDS (32KB); W streamed from L2. ----
// 256 thr = 8 rowgrp x 32 colgrp, thread = 8x4, acc 32 regs, unroll 2 pinned.
__global__ __launch_bounds__(256) void k_gemm(const float* __restrict__ x,
                                              const float* __restrict__ Wm,
                                              float* __restrict__ h, int n) {
  __shared__ float xs[BM * F];   // 32 KB -> ~5 blocks/CU
  int t = threadIdx.x;
  int row0 = blockIdx.x * BM;
  int rows = n - row0; if (rows > BM) rows = BM;
  {
    const float4* x4 = (const float4*)(x + (size_t)row0 * F);
    float4* xs4 = (float4*)xs;
    for (int i = t; i < rows * (F / 4); i += 256) xs4[i] = x4[i];
  }
  __syncthreads();

  int c0 = (t & 31) * 4;
  int r0 = (t >> 5) * 8;
  float acc[8][4] = {{0.f}};
#pragma unroll 2
  for (int k = 0; k < F; k += 4) {
    float4 wv[4];
#pragma unroll
    for (int kk = 0; kk < 4; ++kk) wv[kk] = *(const float4*)&Wm[(size_t)(k + kk) * F + c0];
#pragma unroll
    for (int r = 0; r < 8; ++r) {
      float4 xv = *(const float4*)&xs[(r0 + r) * F + k];
      acc[r][0] = fmaf(xv.x, wv[0].x, acc[r][0]);
      acc[r][1] = fmaf(xv.x, wv[0].y, acc[r][1]);
      acc[r][2] = fmaf(xv.x, wv[0].z, acc[r][2]);
      acc[r][3] = fmaf(xv.x, wv[0].w, acc[r][3]);
      acc[r][0] = fmaf(xv.y, wv[1].x, acc[r][0]);
      acc[r][1] = fmaf(xv.y, wv[1].y, acc[r][1]);
      acc[r][2] = fmaf(xv.y, wv[1].z, acc[r][2]);
      acc[r][3] = fmaf(xv.y, wv[1].w, acc[r][3]);
      acc[r][0] = fmaf(xv.z, wv[2].x, acc[r][0]);
      acc[r][1] = fmaf(xv.z, wv[2].y, acc[r][1]);
      acc[r][2] = fmaf(xv.z, wv[2].z, acc[r][2]);
      acc[r][3] = fmaf(xv.z, wv[2].w, acc[r][3]);
      acc[r][0] = fmaf(xv.w, wv[3].x, acc[r][0]);
      acc[r][1] = fmaf(xv.w, wv[3].y, acc[r][1]);
      acc[r][2] = fmaf(xv.w, wv[3].z, acc[r][2]);
      acc[r][3] = fmaf(xv.w, wv[3].w, acc[r][3]);
    }
  }
#pragma unroll
  for (int r = 0; r < 8; ++r) {
    int gr = row0 + r0 + r;
    if (gr < n) {
      float4 o; o.x = acc[r][0]; o.y = acc[r][1]; o.z = acc[r][2]; o.w = acc[r][3];
      *(float4*)&h[(size_t)gr * F + c0] = o;
    }
  }
}

// ---- CSR gather: one wave per target node, write out once ----
// out[c] = b + dinv[c]^2 * h[c] + sum_j dinv[src_j]*dinv[c]*h[src_j]
__global__ __launch_bounds__(256) void k_gather(const int* __restrict__ rowptr,
                                                const int* __restrict__ src_sorted,
                                                const float* __restrict__ dinv,
                                                const float* __restrict__ h,
                                                const float* __restrict__ b,
                                                float* __restrict__ out, int n) {
  int node = blockIdx.x * 4 + (threadIdx.x >> 6);
  if (node >= n) return;
  int lane = threadIdx.x & 63;
  float dc = dinv[node];
  int beg = rowptr[node], end = rowptr[node + 1];

  float2 hv = *(const float2*)&h[(size_t)node * F + lane * 2];
  float2 bv = *(const float2*)&b[lane * 2];
  float d2 = dc * dc;
  float ax = bv.x + hv.x * d2;
  float ay = bv.y + hv.y * d2;

  for (int chunk = beg; chunk < end; chunk += 64) {
    int m = end - chunk; if (m > 64) m = 64;
    int myidx = 0; float myw = 0.f;
    if (chunk + lane < end) {
      myidx = src_sorted[chunk + lane];
      myw = dinv[myidx];
    }
    for (int j = 0; j < m; ++j) {
      int r = __shfl(myidx, j);
      float w = __shfl(myw, j) * dc;
      float2 hr = *(const float2*)&h[(size_t)r * F + lane * 2];
      ax = fmaf(hr.x, w, ax);
      ay = fmaf(hr.y, w, ay);
    }
  }
  float2 o; o.x = ax; o.y = ay;
  *(float2*)&out[(size_t)node * F + lane * 2] = o;
}

// ---- BN partial stats: per-feature sum / sumsq ----
__global__ __launch_bounds__(256) void k_stats(const float* __restrict__ out,
                                               float* __restrict__ stats, int n) {
  int f = threadIdx.x & (F - 1);
  int half = threadIdx.x >> 7;
  int rpb = (n + gridDim.x - 1) / gridDim.x;
  int r0 = blockIdx.x * rpb;
  int r1 = r0 + rpb; if (r1 > n) r1 = n;
  float s = 0.f, ss = 0.f;
  for (int r = r0 + half; r < r1; r += 2) {
    float v = out[(size_t)r * F + f];
    s += v; ss += v * v;
  }
  __shared__ float sh[2][F][2];
  sh[0][f][half] = s; sh[1][f][half] = ss;
  __syncthreads();
  if (half == 0) {
    atomicAdd(&stats[f], sh[0][f][0] + sh[0][f][1]);
    atomicAdd(&stats[F + f], sh[1][f][0] + sh[1][f][1]);
  }
}

// ---- finalize scale/shift ----
__global__ void k_fin(float* __restrict__ stats, const float* __restrict__ gamma,
                      const float* __restrict__ beta, int n) {
  int f = threadIdx.x;
  if (f >= F) return;
  float inv_n = 1.0f / (float)n;
  float mean = stats[f] * inv_n;
  float var = stats[F + f] * inv_n - mean * mean;
  float scale = gamma[f] * rsqrtf(var + EPSV);
  stats[2 * F + f] = scale;
  stats[3 * F + f] = beta[f] - mean * scale;
}

// ---- apply BN + ReLU in place ----
__global__ __launch_bounds__(256) void k_apply(float* __restrict__ out,
                                               const float* __restrict__ stats, int n) {
  long long i4 = (long long)blockIdx.x * 256 + threadIdx.x;
  if (i4 >= (long long)n * (F / 4)) return;
  int c0 = ((int)i4 & 31) * 4;
  float4 v = *(const float4*)(out + i4 * 4);
  float4 sc = *(const float4*)(stats + 2 * F + c0);
  float4 sf = *(const float4*)(stats + 3 * F + c0);
  float4 o;
  o.x = fmaxf(v.x * sc.x + sf.x, 0.f);
  o.y = fmaxf(v.y * sc.y + sf.y, 0.f);
  o.z = fmaxf(v.z * sc.z + sf.z, 0.f);
  o.w = fmaxf(v.w * sc.w + sf.w, 0.f);
  *(float4*)(out + i4 * 4) = o;
}

extern "C" void kernel_launch(void* const* d_in, const int* in_sizes, int n_in,
                              void* d_out, int out_size, void* d_ws, size_t ws_size,
                              hipStream_t stream) {
  const float* x     = (const float*)d_in[0];
  const int*   ei    = (const int*)d_in[1];
  const float* W     = (const float*)d_in[2];
  const float* b     = (const float*)d_in[3];
  const float* gamma = (const float*)d_in[4];
  const float* beta  = (const float*)d_in[5];
  int n = in_sizes[0] / F;
  int e = in_sizes[1] / 2;
  const int* row = ei;       // sources
  const int* col = ei + e;   // targets

  float* out = (float*)d_out;
  // workspace layout
  float* h          = (float*)d_ws;                      // n*F floats
  float* dinv       = h + (size_t)n * F;                 // n
  float* stats      = dinv + n;                          // 512
  int*   deg        = (int*)(stats + 512);               // n
  int*   rowptr     = deg + n;                           // n+1
  int*   cursor     = rowptr + (n + 1);                  // n
  int*   bsum       = cursor + n;                        // 128
  int*   src_sorted = bsum + 128;                        // e

  int nblk = (n + SB - 1) / SB;

  k_zero <<<(n + 255) / 256, 256, 0, stream>>>(deg, stats, n);
  k_degc <<<(e + 255) / 256, 256, 0, stream>>>(col, deg, e);
  k_scan1<<<nblk, 256, 0, stream>>>(deg, rowptr, bsum, n);
  k_scan2<<<1, 64, 0, stream>>>(bsum, nblk, rowptr, n, e);
  k_scan3<<<(n + 255) / 256, 256, 0, stream>>>(deg, rowptr, cursor, dinv, bsum, n);
  k_fill <<<(e + 255) / 256, 256, 0, stream>>>(row, col, cursor, src_sorted, e);
  k_gemm <<<(n + BM - 1) / BM, 256, 0, stream>>>(x, W, h, n);
  k_gather<<<(n + 3) / 4, 256, 0, stream>>>(rowptr, src_sorted, dinv, h, b, out, n);
  k_stats<<<400, 256, 0, stream>>>(out, stats, n);
  k_fin  <<<1, F, 0, stream>>>(stats, gamma, beta, n);
  k_apply<<<(int)(((long long)n * (F / 4) + 255) / 256), 256, 0, stream>>>(out, stats, n);
}